// Round 12
// baseline (326.752 us; speedup 1.0000x reference)
//
#include <hip/hip_runtime.h>
#include <stdint.h>

// EETQLinear w8a16: out[m,n] = (sum_k x[m,k]*wq[k,n]) * scale[n] + bias[n]
// M=8192, K=4096, N=4096. Dtypes (r3/r4-verified): x/scale/bias/out f32, wq int32.
// v12: WAVE-GROUP PHASE OFFSET on r10's 4-buffer BK=32 chassis. Waves 0-3 (one
//      per SIMD) compute tile i; waves 4-7 (second wave per SIMD) compute tile
//      i-1 with fragments PRE-READ before the barrier -> their MFMA overlaps the
//      even waves' read burst. Buf3 zero-filled for odd's phantom tile -1;
//      odd epilogue computes tile 127. Stage lead 2 tiles, vmcnt(4).

typedef __attribute__((ext_vector_type(4))) float     f32x4;
typedef __attribute__((ext_vector_type(8))) _Float16  f16x8;

#define M_DIM 8192
#define N_DIM 4096
#define K_DIM 4096

// ---------------- prologue kernels (r4-verified) ----------------
__global__ __launch_bounds__(256) void convert_x_to_f16(const float* __restrict__ x,
                                                        _Float16* __restrict__ Xh) {
    const size_t i = ((size_t)blockIdx.x * 256 + threadIdx.x) * 8;
    float4 v0 = *(const float4*)(x + i);
    float4 v1 = *(const float4*)(x + i + 4);
    f16x8 h;
    h[0] = (_Float16)v0.x; h[1] = (_Float16)v0.y; h[2] = (_Float16)v0.z; h[3] = (_Float16)v0.w;
    h[4] = (_Float16)v1.x; h[5] = (_Float16)v1.y; h[6] = (_Float16)v1.z; h[7] = (_Float16)v1.w;
    *(f16x8*)(Xh + i) = h;
}

__global__ __launch_bounds__(256) void dequant_w_to_f16(const int* __restrict__ wq,
                                                        _Float16* __restrict__ Wt) {
    __shared__ _Float16 tile[64][65];
    const int n0 = blockIdx.x * 64;
    const int k0 = blockIdx.y * 64;
    const int t  = threadIdx.x;
    const int r  = t >> 2;
    const int c0 = (t & 3) * 16;
    const int* src = wq + (size_t)(k0 + r) * N_DIM + n0 + c0;
#pragma unroll
    for (int j = 0; j < 4; ++j) {
        int4 q = *(const int4*)(src + j * 4);
        tile[c0 + j * 4 + 0][r] = (_Float16)q.x;
        tile[c0 + j * 4 + 1][r] = (_Float16)q.y;
        tile[c0 + j * 4 + 2][r] = (_Float16)q.z;
        tile[c0 + j * 4 + 3][r] = (_Float16)q.w;
    }
    __syncthreads();
    const int nn  = t >> 2;
    const int cc0 = (t & 3) * 16;
    _Float16 vals[16] __attribute__((aligned(16)));
#pragma unroll
    for (int j = 0; j < 16; ++j) vals[j] = tile[nn][cc0 + j];
    _Float16* dst = Wt + (size_t)(n0 + nn) * K_DIM + k0 + cc0;
    *(float4*)(dst + 0) = *(const float4*)(vals + 0);
    *(float4*)(dst + 8) = *(const float4*)(vals + 8);
}

// ---------------- 4-buffer BK=32 GEMM with wave-group phase offset ----------------
#define AS1C(p) (const __attribute__((address_space(1))) void*)(p)
#define AS3C(p) (__attribute__((address_space(3))) void*)(p)

#define STAGE_TILE(BB, tl) do {                                                       \
    __builtin_amdgcn_global_load_lds(AS1C(aStageBase + (size_t)(tl) * 32),            \
        AS3C(ldsBase + (BB) + t * 16), 16, 0, 0);                                     \
    __builtin_amdgcn_global_load_lds(AS1C(aStageBase + aHalfJump + (size_t)(tl) * 32),\
        AS3C(ldsBase + (BB) + 8192 + t * 16), 16, 0, 0);                              \
    __builtin_amdgcn_global_load_lds(AS1C(bStageBase + (size_t)(tl) * 32),            \
        AS3C(ldsBase + (BB) + 16384 + t * 16), 16, 0, 0);                             \
    __builtin_amdgcn_global_load_lds(AS1C(bStageBase + bHalfJump + (size_t)(tl) * 32),\
        AS3C(ldsBase + (BB) + 24576 + t * 16), 16, 0, 0);                             \
} while (0)

#define DSR(dst, addr, IMM) \
    asm volatile("ds_read_b128 %0, %1 offset:%c2" : "=v"(dst) : "v"(addr), "i"(IMM))

#define READS(AR, BR, IB)                                    \
    DSR(a0, AR, (IB) + 0 * 1024);                            \
    DSR(a1, AR, (IB) + 1 * 1024);                            \
    DSR(a2, AR, (IB) + 2 * 1024);                            \
    DSR(a3, AR, (IB) + 3 * 1024);                            \
    DSR(a4, AR, (IB) + 4 * 1024);                            \
    DSR(a5, AR, (IB) + 5 * 1024);                            \
    DSR(a6, AR, (IB) + 6 * 1024);                            \
    DSR(a7, AR, (IB) + 7 * 1024);                            \
    DSR(b0, BR, (IB) + 16384 + 0 * 1024);                    \
    DSR(b1, BR, (IB) + 16384 + 1 * 1024);                    \
    DSR(b2, BR, (IB) + 16384 + 2 * 1024);                    \
    DSR(b3, BR, (IB) + 16384 + 3 * 1024)

#define MM(AI, NI, AV, BV) \
    acc[AI][NI] = __builtin_amdgcn_mfma_f32_16x16x32_f16(AV, BV, acc[AI][NI], 0, 0, 0)

#define MFMA32()                                                          \
    MM(0, 0, a0, b0); MM(0, 1, a0, b1); MM(0, 2, a0, b2); MM(0, 3, a0, b3); \
    MM(1, 0, a1, b0); MM(1, 1, a1, b1); MM(1, 2, a1, b2); MM(1, 3, a1, b3); \
    MM(2, 0, a2, b0); MM(2, 1, a2, b1); MM(2, 2, a2, b2); MM(2, 3, a2, b3); \
    MM(3, 0, a3, b0); MM(3, 1, a3, b1); MM(3, 2, a3, b2); MM(3, 3, a3, b3); \
    MM(4, 0, a4, b0); MM(4, 1, a4, b1); MM(4, 2, a4, b2); MM(4, 3, a4, b3); \
    MM(5, 0, a5, b0); MM(5, 1, a5, b1); MM(5, 2, a5, b2); MM(5, 3, a5, b3); \
    MM(6, 0, a6, b0); MM(6, 1, a6, b1); MM(6, 2, a6, b2); MM(6, 3, a6, b3); \
    MM(7, 0, a7, b0); MM(7, 1, a7, b1); MM(7, 2, a7, b2); MM(7, 3, a7, b3)

#define BARR()  __builtin_amdgcn_s_barrier()
#define SB0()   __builtin_amdgcn_sched_barrier(0)
#define LGKM0() do { asm volatile("s_waitcnt lgkmcnt(0)" ::: "memory"); SB0(); } while (0)
#define VMC4()  asm volatile("s_waitcnt vmcnt(4)" ::: "memory")
#define PRIO1() __builtin_amdgcn_s_setprio(1)
#define PRIO0() __builtin_amdgcn_s_setprio(0)

#define INTERVAL(CRA, CRB, CIB, PRA, PRB, PIB, SBB, tl) do {                          \
    if (odd) { READS(PRA, PRB, PIB); }      /* data landed at BARR(j-1): no wait */   \
    VMC4();                                 /* my 4 DMA of tile j landed */           \
    BARR();                                 /* ... and everyone's */                  \
    STAGE_TILE((SBB), (tl));                                                          \
    if (!odd) { READS(CRA, CRB, CIB); }                                               \
    LGKM0(); PRIO1(); MFMA32(); PRIO0();                                              \
} while (0)

__global__ __launch_bounds__(512, 2) void gemm_po(const _Float16* __restrict__ Xh,
                                                  const _Float16* __restrict__ Wt,
                                                  const float* __restrict__ scale,
                                                  const float* __restrict__ bias,
                                                  float* __restrict__ C) {
    __shared__ __attribute__((aligned(128))) _Float16 L[65536];   // 128 KB
    char* ldsBase = (char*)L;

    // T1: XCD-aware bijective swizzle (512 blocks, 512 % 8 == 0)
    const int bid = blockIdx.x;
    const int swz = (bid & 7) * 64 + (bid >> 3);
    const int bm  = swz >> 4;            // 0..31
    const int bn  = swz & 15;            // 0..15

    const int t  = threadIdx.x;          // 0..511
    const int l  = t & 63;
    const int w  = t >> 6;               // 8 waves; SIMD = w&3 (round-robin)
    const int wm = (w & 3) >> 1;         // output slot from w&3
    const int wn = ((w & 3) & 1) * 2 + (w >> 2);  // w and w+4: same wm, different wn
    const int odd = __builtin_amdgcn_readfirstlane(w >> 2);  // uniform branch

    const int lr = l & 15, lh = l >> 4;

    // staging (r10-verified, 0 conflicts): row t>>2 (+128), slot t&3,
    // source slot pre-XORed by ((row>>1)&3)
    const int rowIdx = t >> 2;                                  // 0..127
    const int kbSw   = ((t & 3) ^ ((rowIdx >> 1) & 3)) * 16;    // bytes
    const _Float16* aStageBase = Xh + (size_t)(bm * 256 + rowIdx) * K_DIM + (kbSw >> 1);
    const _Float16* bStageBase = Wt + (size_t)(bn * 256 + rowIdx) * K_DIM + (kbSw >> 1);
    const size_t aHalfJump = (size_t)128 * K_DIM;
    const size_t bHalfJump = (size_t)128 * K_DIM;

    // ds_read lane addresses (r10-verified): byte = row*64 + xr; frags +i*1024
    const uint32_t xr   = (uint32_t)((lh ^ ((lr >> 1) & 3)) << 4);
    const uint32_t aoff = (uint32_t)((wm * 128 + lr) * 64) + xr;
    const uint32_t boff = (uint32_t)((wn * 64 + lr) * 64) + xr;  // +16384 via imm
    const uint32_t aLo  = (uint32_t)(uintptr_t)L + aoff;           // buffers 0,1
    const uint32_t aHi  = (uint32_t)(uintptr_t)L + 65536 + aoff;   // buffers 2,3
    const uint32_t bLo  = (uint32_t)(uintptr_t)L + boff;
    const uint32_t bHi  = (uint32_t)(uintptr_t)L + 65536 + boff;

    f16x8 a0, a1, a2, a3, a4, a5, a6, a7, b0, b1, b2, b3;
    f32x4 acc[8][4] = {};

    // zero buf3 (odd waves' phantom tile -1 contributes exactly 0)
    {
        f16x8 z = {};
#pragma unroll
        for (int k = 0; k < 4; ++k)
            *(f16x8*)(ldsBase + 98304 + t * 64 + k * 16) = z;
    }
    __syncthreads();

    // prologue: stage tiles 0,1 into buffers 0,1
    STAGE_TILE(0 * 32768, 0);
    STAGE_TILE(1 * 32768, 1);

#pragma unroll 1
    for (int it = 0; it < 32; ++it) {             // 128 tiles, 4 per iteration
        const int base = it * 4;
        const int t2 = (base + 2) & 127;
        const int t3 = (base + 3) & 127;
        const int t4 = (base + 4) & 127;
        const int t5 = (base + 5) & 127;
        INTERVAL(aLo, bLo, 0,      aHi, bHi, 32768, 2 * 32768, t2);  // cur b0, prev b3
        INTERVAL(aLo, bLo, 32768,  aLo, bLo, 0,     3 * 32768, t3);  // cur b1, prev b0
        INTERVAL(aHi, bHi, 0,      aLo, bLo, 32768, 0 * 32768, t4);  // cur b2, prev b1
        INTERVAL(aHi, bHi, 32768,  aHi, bHi, 0,     1 * 32768, t5);  // cur b3, prev b2
    }
    // odd-wave epilogue: tile 127 (buf3; staging never touched it afterwards)
    if (odd) {
        READS(aHi, bHi, 32768);
        LGKM0(); PRIO1(); MFMA32(); PRIO0();
    }
    asm volatile("s_waitcnt vmcnt(0)" ::: "memory");  // drain dangling prefetches

    // epilogue: C/D layout col = lane&15, row = (lane>>4)*4 + reg  [m89-verified]
    const int col0 = bn * 256 + wn * 64 + lr;
    const int row0 = bm * 256 + wm * 128 + lh * 4;
    float sc[4], bi[4];
#pragma unroll
    for (int ni = 0; ni < 4; ++ni) {
        sc[ni] = scale[col0 + ni * 16];
        bi[ni] = bias[col0 + ni * 16];
    }
#pragma unroll
    for (int ai = 0; ai < 8; ++ai)
#pragma unroll
        for (int r = 0; r < 4; ++r) {
            const size_t rowOff = (size_t)(row0 + ai * 16 + r) * N_DIM;
#pragma unroll
            for (int ni = 0; ni < 4; ++ni)
                C[rowOff + col0 + ni * 16] = acc[ai][ni][r] * sc[ni] + bi[ni];
        }
}

extern "C" void kernel_launch(void* const* d_in, const int* in_sizes, int n_in,
                              void* d_out, int out_size, void* d_ws, size_t ws_size,
                              hipStream_t stream) {
    const float* x     = (const float*)d_in[0];
    const int*   wq    = (const int*)d_in[1];
    const float* scale = (const float*)d_in[2];
    const float* bias  = (const float*)d_in[3];
    float* out = (float*)d_out;

    const size_t needW = (size_t)N_DIM * K_DIM * sizeof(_Float16);   // 33.5 MB
    _Float16* Wt = (_Float16*)d_ws;
    _Float16* Xh = (_Float16*)((char*)d_ws + needW);                 // ws >= 100.7MB (r4)

    dim3 tgrid(N_DIM / 64, K_DIM / 64);
    dequant_w_to_f16<<<tgrid, 256, 0, stream>>>(wq, Wt);
    convert_x_to_f16<<<((size_t)M_DIM * K_DIM) / (256 * 8), 256, 0, stream>>>(x, Xh);

    const int nblocks = (M_DIM / 256) * (N_DIM / 256);               // 512
    gemm_po<<<nblocks, 512, 0, stream>>>(Xh, Wt, scale, bias, out);
}

// Round 13
// 284.204 us; speedup vs baseline: 1.1497x; 1.1497x over previous
//
#include <hip/hip_runtime.h>
#include <stdint.h>

// EETQLinear w8a16: out[m,n] = (sum_k x[m,k]*wq[k,n]) * scale[n] + bias[n]
// M=8192, K=4096, N=4096. Dtypes (r3/r4-verified): x/scale/bias/out f32, wq int32.
// v13: CROSS-WINDOW READ PIPELINE on r10's 4-buffer BK=32 chassis (0 conflicts).
//      Window i: LGKM0 -> MFMA(tile i) -> READS(tile i+1) -> STAGE(tile i+3)
//      -> VMC4 -> BARR. Reads issued a full window before their lgkm-wait, so
//      the post-barrier path is lgkm(~0)+MFMA; LDS port drains under MFMA.

typedef __attribute__((ext_vector_type(4))) float     f32x4;
typedef __attribute__((ext_vector_type(8))) _Float16  f16x8;

#define M_DIM 8192
#define N_DIM 4096
#define K_DIM 4096

// ---------------- prologue kernels (r4-verified) ----------------
__global__ __launch_bounds__(256) void convert_x_to_f16(const float* __restrict__ x,
                                                        _Float16* __restrict__ Xh) {
    const size_t i = ((size_t)blockIdx.x * 256 + threadIdx.x) * 8;
    float4 v0 = *(const float4*)(x + i);
    float4 v1 = *(const float4*)(x + i + 4);
    f16x8 h;
    h[0] = (_Float16)v0.x; h[1] = (_Float16)v0.y; h[2] = (_Float16)v0.z; h[3] = (_Float16)v0.w;
    h[4] = (_Float16)v1.x; h[5] = (_Float16)v1.y; h[6] = (_Float16)v1.z; h[7] = (_Float16)v1.w;
    *(f16x8*)(Xh + i) = h;
}

__global__ __launch_bounds__(256) void dequant_w_to_f16(const int* __restrict__ wq,
                                                        _Float16* __restrict__ Wt) {
    __shared__ _Float16 tile[64][65];
    const int n0 = blockIdx.x * 64;
    const int k0 = blockIdx.y * 64;
    const int t  = threadIdx.x;
    const int r  = t >> 2;
    const int c0 = (t & 3) * 16;
    const int* src = wq + (size_t)(k0 + r) * N_DIM + n0 + c0;
#pragma unroll
    for (int j = 0; j < 4; ++j) {
        int4 q = *(const int4*)(src + j * 4);
        tile[c0 + j * 4 + 0][r] = (_Float16)q.x;
        tile[c0 + j * 4 + 1][r] = (_Float16)q.y;
        tile[c0 + j * 4 + 2][r] = (_Float16)q.z;
        tile[c0 + j * 4 + 3][r] = (_Float16)q.w;
    }
    __syncthreads();
    const int nn  = t >> 2;
    const int cc0 = (t & 3) * 16;
    _Float16 vals[16] __attribute__((aligned(16)));
#pragma unroll
    for (int j = 0; j < 16; ++j) vals[j] = tile[nn][cc0 + j];
    _Float16* dst = Wt + (size_t)(n0 + nn) * K_DIM + k0 + cc0;
    *(float4*)(dst + 0) = *(const float4*)(vals + 0);
    *(float4*)(dst + 8) = *(const float4*)(vals + 8);
}

// ---------------- 4-buffer BK=32 GEMM, cross-window read pipeline ----------------
#define AS1C(p) (const __attribute__((address_space(1))) void*)(p)
#define AS3C(p) (__attribute__((address_space(3))) void*)(p)

#define STAGE_TILE(BB, tl) do {                                                       \
    __builtin_amdgcn_global_load_lds(AS1C(aStageBase + (size_t)(tl) * 32),            \
        AS3C(ldsBase + (BB) + t * 16), 16, 0, 0);                                     \
    __builtin_amdgcn_global_load_lds(AS1C(aStageBase + aHalfJump + (size_t)(tl) * 32),\
        AS3C(ldsBase + (BB) + 8192 + t * 16), 16, 0, 0);                              \
    __builtin_amdgcn_global_load_lds(AS1C(bStageBase + (size_t)(tl) * 32),            \
        AS3C(ldsBase + (BB) + 16384 + t * 16), 16, 0, 0);                             \
    __builtin_amdgcn_global_load_lds(AS1C(bStageBase + bHalfJump + (size_t)(tl) * 32),\
        AS3C(ldsBase + (BB) + 24576 + t * 16), 16, 0, 0);                             \
} while (0)

#define DSR(dst, addr, IMM) \
    asm volatile("ds_read_b128 %0, %1 offset:%c2" : "=v"(dst) : "v"(addr), "i"(IMM))

// 12 fragment reads of buffer pair (AR,BR) at imm base IB (0 or 32768)
#define READS(AR, BR, IB)                                    \
    DSR(a0, AR, (IB) + 0 * 1024);                            \
    DSR(a1, AR, (IB) + 1 * 1024);                            \
    DSR(a2, AR, (IB) + 2 * 1024);                            \
    DSR(a3, AR, (IB) + 3 * 1024);                            \
    DSR(a4, AR, (IB) + 4 * 1024);                            \
    DSR(a5, AR, (IB) + 5 * 1024);                            \
    DSR(a6, AR, (IB) + 6 * 1024);                            \
    DSR(a7, AR, (IB) + 7 * 1024);                            \
    DSR(b0, BR, (IB) + 16384 + 0 * 1024);                    \
    DSR(b1, BR, (IB) + 16384 + 1 * 1024);                    \
    DSR(b2, BR, (IB) + 16384 + 2 * 1024);                    \
    DSR(b3, BR, (IB) + 16384 + 3 * 1024)

#define MM(AI, NI, AV, BV) \
    acc[AI][NI] = __builtin_amdgcn_mfma_f32_16x16x32_f16(AV, BV, acc[AI][NI], 0, 0, 0)

#define MFMA32()                                                          \
    MM(0, 0, a0, b0); MM(0, 1, a0, b1); MM(0, 2, a0, b2); MM(0, 3, a0, b3); \
    MM(1, 0, a1, b0); MM(1, 1, a1, b1); MM(1, 2, a1, b2); MM(1, 3, a1, b3); \
    MM(2, 0, a2, b0); MM(2, 1, a2, b1); MM(2, 2, a2, b2); MM(2, 3, a2, b3); \
    MM(3, 0, a3, b0); MM(3, 1, a3, b1); MM(3, 2, a3, b2); MM(3, 3, a3, b3); \
    MM(4, 0, a4, b0); MM(4, 1, a4, b1); MM(4, 2, a4, b2); MM(4, 3, a4, b3); \
    MM(5, 0, a5, b0); MM(5, 1, a5, b1); MM(5, 2, a5, b2); MM(5, 3, a5, b3); \
    MM(6, 0, a6, b0); MM(6, 1, a6, b1); MM(6, 2, a6, b2); MM(6, 3, a6, b3); \
    MM(7, 0, a7, b0); MM(7, 1, a7, b1); MM(7, 2, a7, b2); MM(7, 3, a7, b3)

#define BARR()  __builtin_amdgcn_s_barrier()
#define SB0()   __builtin_amdgcn_sched_barrier(0)
#define LGKM0() do { asm volatile("s_waitcnt lgkmcnt(0)" ::: "memory"); SB0(); } while (0)
#define VMC4()  asm volatile("s_waitcnt vmcnt(4)" ::: "memory")
#define PRIO1() __builtin_amdgcn_s_setprio(1)
#define PRIO0() __builtin_amdgcn_s_setprio(0)

// Window for tile j (buffer slots static): MFMA consumes frags read LAST window;
// then issue next tile's reads + the stage; counted vmcnt; one barrier.
// Safety: READS(j+1) — landing confirmed by W(j-1)'s VMC4 + BARR(j).
//         STAGE -> buf (j+3)&3 = tile (j-1)'s buffer; its reads were lgkm0-drained
//         at the start of W(j-1), two barriers before any wave reaches this STAGE.
#define WINDOW(RA, RB, RIB, SBB, tl) do {                                             \
    LGKM0();                                /* frags of tile j (issued W(j-1)) */     \
    PRIO1(); MFMA32(); PRIO0();                                                       \
    READS(RA, RB, RIB);                     /* tile j+1 -> regs, in flight */         \
    STAGE_TILE((SBB), (tl));                /* tile j+3 */                            \
    VMC4();                                 /* drain tile j+2: ready for W(j+1) */    \
    BARR();                                                                           \
} while (0)

__global__ __launch_bounds__(512, 2) void gemm_cw(const _Float16* __restrict__ Xh,
                                                  const _Float16* __restrict__ Wt,
                                                  const float* __restrict__ scale,
                                                  const float* __restrict__ bias,
                                                  float* __restrict__ C) {
    __shared__ __attribute__((aligned(128))) _Float16 L[65536];   // 128 KB, 4 x 32KB
    char* ldsBase = (char*)L;

    // T1: XCD-aware bijective swizzle (512 blocks, 512 % 8 == 0)
    const int bid = blockIdx.x;
    const int swz = (bid & 7) * 64 + (bid >> 3);
    const int bm  = swz >> 4;            // 0..31
    const int bn  = swz & 15;            // 0..15

    const int t  = threadIdx.x;          // 0..511
    const int l  = t & 63;
    const int w  = t >> 6;               // 8 waves: 2(M) x 4(N)
    const int wm = w >> 2, wn = w & 3;   // wave out: 128 rows x 64 cols
    const int lr = l & 15, lh = l >> 4;

    // staging (r10-verified, 0 conflicts): row t>>2 (+128 half), slot t&3,
    // source slot pre-XORed by ((row>>1)&3)
    const int rowIdx = t >> 2;                                  // 0..127
    const int kbSw   = ((t & 3) ^ ((rowIdx >> 1) & 3)) * 16;    // bytes
    const _Float16* aStageBase = Xh + (size_t)(bm * 256 + rowIdx) * K_DIM + (kbSw >> 1);
    const _Float16* bStageBase = Wt + (size_t)(bn * 256 + rowIdx) * K_DIM + (kbSw >> 1);
    const size_t aHalfJump = (size_t)128 * K_DIM;
    const size_t bHalfJump = (size_t)128 * K_DIM;

    // ds_read lane addresses (r10-verified): byte = row*64 + xr; frags +i*1024
    const uint32_t xr   = (uint32_t)((lh ^ ((lr >> 1) & 3)) << 4);
    const uint32_t aoff = (uint32_t)((wm * 128 + lr) * 64) + xr;
    const uint32_t boff = (uint32_t)((wn * 64 + lr) * 64) + xr;  // +16384 via imm
    const uint32_t aLo  = (uint32_t)(uintptr_t)L + aoff;           // buffers 0,1
    const uint32_t aHi  = (uint32_t)(uintptr_t)L + 65536 + aoff;   // buffers 2,3
    const uint32_t bLo  = (uint32_t)(uintptr_t)L + boff;
    const uint32_t bHi  = (uint32_t)(uintptr_t)L + 65536 + boff;

    f16x8 a0, a1, a2, a3, a4, a5, a6, a7, b0, b1, b2, b3;
    f32x4 acc[8][4] = {};

    // prologue: stage tiles 0,1,2 into buffers 0,1,2; confirm tiles 0,1; read tile 0
    STAGE_TILE(0 * 32768, 0);
    STAGE_TILE(1 * 32768, 1);
    STAGE_TILE(2 * 32768, 2);
    VMC4();                    // 12 outstanding -> <=4: tiles 0,1 landed
    BARR();
    READS(aLo, bLo, 0);        // tile 0 frags in flight; waited at first LGKM0

#pragma unroll 1
    for (int it = 0; it < 32; ++it) {             // 128 windows, 4 per iteration
        const int base = it * 4;
        // tile j=base+0: read t(j+1) buf1, stage t(j+3) -> buf3
        WINDOW(aLo, bLo, 32768, 3 * 32768, (base + 3) & 127);
        // tile j+1: read t(j+2) buf2, stage t(j+4) -> buf0
        WINDOW(aHi, bHi, 0,     0 * 32768, (base + 4) & 127);
        // tile j+2: read t(j+3) buf3, stage t(j+5) -> buf1
        WINDOW(aHi, bHi, 32768, 1 * 32768, (base + 5) & 127);
        // tile j+3: read t(j+4) buf0, stage t(j+6) -> buf2
        WINDOW(aLo, bLo, 0,     2 * 32768, (base + 6) & 127);
    }
    // tail: window 127 already ran MFMA(127); its trailing READS/STAGE are dead.
    asm volatile("s_waitcnt lgkmcnt(0)" ::: "memory");
    asm volatile("s_waitcnt vmcnt(0)" ::: "memory");

    // epilogue: C/D layout col = lane&15, row = (lane>>4)*4 + reg  [m89-verified]
    const int col0 = bn * 256 + wn * 64 + lr;
    const int row0 = bm * 256 + wm * 128 + lh * 4;
    float sc[4], bi[4];
#pragma unroll
    for (int ni = 0; ni < 4; ++ni) {
        sc[ni] = scale[col0 + ni * 16];
        bi[ni] = bias[col0 + ni * 16];
    }
#pragma unroll
    for (int ai = 0; ai < 8; ++ai)
#pragma unroll
        for (int r = 0; r < 4; ++r) {
            const size_t rowOff = (size_t)(row0 + ai * 16 + r) * N_DIM;
#pragma unroll
            for (int ni = 0; ni < 4; ++ni)
                C[rowOff + col0 + ni * 16] = acc[ai][ni][r] * sc[ni] + bi[ni];
        }
}

extern "C" void kernel_launch(void* const* d_in, const int* in_sizes, int n_in,
                              void* d_out, int out_size, void* d_ws, size_t ws_size,
                              hipStream_t stream) {
    const float* x     = (const float*)d_in[0];
    const int*   wq    = (const int*)d_in[1];
    const float* scale = (const float*)d_in[2];
    const float* bias  = (const float*)d_in[3];
    float* out = (float*)d_out;

    const size_t needW = (size_t)N_DIM * K_DIM * sizeof(_Float16);   // 33.5 MB
    _Float16* Wt = (_Float16*)d_ws;
    _Float16* Xh = (_Float16*)((char*)d_ws + needW);                 // ws >= 100.7MB (r4)

    dim3 tgrid(N_DIM / 64, K_DIM / 64);
    dequant_w_to_f16<<<tgrid, 256, 0, stream>>>(wq, Wt);
    convert_x_to_f16<<<((size_t)M_DIM * K_DIM) / (256 * 8), 256, 0, stream>>>(x, Xh);

    const int nblocks = (M_DIM / 256) * (N_DIM / 256);               // 512
    gemm_cw<<<nblocks, 512, 0, stream>>>(Xh, Wt, scale, bias, out);
}